// Round 1
// baseline (317.967 us; speedup 1.0000x reference)
//
#include <hip/hip_runtime.h>
#include <math.h>

#define BB 4
#define NN 256
#define HH 128
#define RTOT (BB*NN)          // 1024 node rows
#define ME_ (BB*NN*NN)        // 262144 edge rows

// workspace float offsets
#define VX_OFF   0            // 1024*128
#define VNX_OFF  131072
#define UX_OFF   262144
#define NUM_OFF  393216
#define DEN_OFF  524288
#define PSUM_OFF 655360       // per-(b,i)-block BN-e partial sums  [1024][128]
#define PSQ_OFF  786432
#define SCE_OFF  917504       // [128]
#define SHE_OFF  917632       // [128]

// ---------------------------------------------------------------------------
// Kernel A: Vx = x@Ve^T+b, Vnx = x@Vn^T+b, Ux = x@Un^T+b   (1024 rows, H=128)
// ---------------------------------------------------------------------------
__global__ __launch_bounds__(256) void k_linx(
    const float* __restrict__ x,
    const float* __restrict__ Ve_w, const float* __restrict__ Ve_b,
    const float* __restrict__ Vn_w, const float* __restrict__ Vn_b,
    const float* __restrict__ Un_w, const float* __restrict__ Un_b,
    float* ws)
{
    __shared__ float xs[8 * 128];
    int t = threadIdx.x;
    int rowbase = blockIdx.x * 8;

    // stage 8 x-rows (1024 floats = 256 float4)
    const float4* xg = (const float4*)(x + (size_t)rowbase * 128);
    ((float4*)xs)[t] = xg[t];
    __syncthreads();

    int h = t & 127, rh = t >> 7;     // thread h, row-parity
    float accV[4], accN[4], accU[4];
    float bV = Ve_b[h], bN = Vn_b[h], bU = Un_b[h];
    #pragma unroll
    for (int q = 0; q < 4; ++q) { accV[q] = bV; accN[q] = bN; accU[q] = bU; }

    const float4* wV = (const float4*)(Ve_w + (size_t)h * 128);
    const float4* wN = (const float4*)(Vn_w + (size_t)h * 128);
    const float4* wU = (const float4*)(Un_w + (size_t)h * 128);

    #pragma unroll 4
    for (int k4 = 0; k4 < 32; ++k4) {
        float4 wv = wV[k4], wn = wN[k4], wu = wU[k4];
        #pragma unroll
        for (int q = 0; q < 4; ++q) {
            float4 xv = *(const float4*)&xs[(rh + 2 * q) * 128 + k4 * 4];
            accV[q] += xv.x*wv.x + xv.y*wv.y + xv.z*wv.z + xv.w*wv.w;
            accN[q] += xv.x*wn.x + xv.y*wn.y + xv.z*wn.z + xv.w*wn.w;
            accU[q] += xv.x*wu.x + xv.y*wu.y + xv.z*wu.z + xv.w*wu.w;
        }
    }
    #pragma unroll
    for (int q = 0; q < 4; ++q) {
        size_t idx = (size_t)(rowbase + rh + 2 * q) * 128 + h;
        ws[VX_OFF  + idx] = accV[q];
        ws[VNX_OFF + idx] = accN[q];
        ws[UX_OFF  + idx] = accU[q];
    }
}

// ---------------------------------------------------------------------------
// Kernel B: per (b,i): e_feat = e@Ue^T + Ue_b + Vx_i + Vx_j  (store to out_e),
// gates=sigmoid, num/den row sums, BN-e partial sums.
// ---------------------------------------------------------------------------
__global__ __launch_bounds__(256) void k_edge(
    const float* __restrict__ e,
    const float* __restrict__ Ue_w, const float* __restrict__ Ue_b,
    float* out_e, float* ws)
{
    __shared__ float Wl[128 * 128];   // 64 KB, XOR-swizzled by 16B unit
    __shared__ float Al[32 * 128];    // 16 KB e-tile; reused as partials [4][8][128]
    int t  = threadIdx.x;
    int bi = blockIdx.x;              // (b,i) row, 0..1023
    int b  = bi >> 8;
    int th = t & 31, tj = t >> 5;     // h-lane (32), j-group (8)

    // stage W swizzled: slot (r, u) <- global (r, u ^ (r&31))  [XOR involution]
    float4* Wl4 = (float4*)Wl;
    const float4* Wg4 = (const float4*)Ue_w;
    #pragma unroll
    for (int p = 0; p < 16; ++p) {
        int s = t + 256 * p;
        int r = s >> 5, ug = s & 31;
        Wl4[(r << 5) + (ug ^ (r & 31))] = Wg4[s];
    }

    const float* Vx  = ws + VX_OFF;
    const float* Vnx = ws + VNX_OFF;
    float bias4[4];
    #pragma unroll
    for (int hh = 0; hh < 4; ++hh) {
        int h = th + 32 * hh;
        bias4[hh] = Ue_b[h] + Vx[(size_t)bi * 128 + h];
    }

    float num_acc[4] = {0,0,0,0}, den_acc[4] = {0,0,0,0};
    float se_acc[4]  = {0,0,0,0}, sq_acc[4]  = {0,0,0,0};

    const float4* eg4 = (const float4*)(e + (size_t)bi * (NN * HH));
    float4* Al4 = (float4*)Al;
    float* oute = out_e + (size_t)bi * (NN * HH);

    for (int jb = 0; jb < 8; ++jb) {
        __syncthreads();                       // protect Al (and W on jb=0)
        #pragma unroll
        for (int p = 0; p < 4; ++p) {
            int s = t + 256 * p;
            Al4[s] = eg4[jb * 1024 + s];
        }
        __syncthreads();

        float acc[4][4];
        #pragma unroll
        for (int jj = 0; jj < 4; ++jj)
            #pragma unroll
            for (int hh = 0; hh < 4; ++hh) acc[jj][hh] = 0.0f;

        #pragma unroll 4
        for (int k4 = 0; k4 < 32; ++k4) {
            float4 w0 = Wl4[((th +  0) << 5) + (k4 ^ th)];
            float4 w1 = Wl4[((th + 32) << 5) + (k4 ^ th)];
            float4 w2 = Wl4[((th + 64) << 5) + (k4 ^ th)];
            float4 w3 = Wl4[((th + 96) << 5) + (k4 ^ th)];
            #pragma unroll
            for (int jj = 0; jj < 4; ++jj) {
                float4 a = Al4[((tj * 4 + jj) << 5) + k4];
                acc[jj][0] += a.x*w0.x + a.y*w0.y + a.z*w0.z + a.w*w0.w;
                acc[jj][1] += a.x*w1.x + a.y*w1.y + a.z*w1.z + a.w*w1.w;
                acc[jj][2] += a.x*w2.x + a.y*w2.y + a.z*w2.z + a.w*w2.w;
                acc[jj][3] += a.x*w3.x + a.y*w3.y + a.z*w3.z + a.w*w3.w;
            }
        }

        // epilogue: bias + Vx_j, store e_feat, sigmoid, accumulate
        #pragma unroll
        for (int jj = 0; jj < 4; ++jj) {
            int j = jb * 32 + tj * 4 + jj;
            const float* VxJ = Vx  + (size_t)(b * 256 + j) * 128;
            const float* VnJ = Vnx + (size_t)(b * 256 + j) * 128;
            float* orow = oute + (size_t)j * 128;
            #pragma unroll
            for (int hh = 0; hh < 4; ++hh) {
                int h = th + 32 * hh;
                float v = acc[jj][hh] + bias4[hh] + VxJ[h];
                orow[h] = v;
                float g = 1.0f / (1.0f + __expf(-v));
                num_acc[hh] += g * VnJ[h];
                den_acc[hh] += g;
                se_acc[hh]  += v;
                sq_acc[hh]  += v * v;
            }
        }
    }

    // block reduce over tj groups (reuse Al as [4][8][128])
    __syncthreads();
    float* part = Al;
    #pragma unroll
    for (int hh = 0; hh < 4; ++hh) {
        int h = th + 32 * hh;
        part[0 * 1024 + tj * 128 + h] = num_acc[hh];
        part[1 * 1024 + tj * 128 + h] = den_acc[hh];
        part[2 * 1024 + tj * 128 + h] = se_acc[hh];
        part[3 * 1024 + tj * 128 + h] = sq_acc[hh];
    }
    __syncthreads();
    if (t < 128) {
        int h = t;
        float sn = 0.f, sd = 0.f;
        #pragma unroll
        for (int r = 0; r < 8; ++r) {
            sn += part[0 * 1024 + r * 128 + h];
            sd += part[1 * 1024 + r * 128 + h];
        }
        ws[NUM_OFF + (size_t)bi * 128 + h] = sn;
        ws[DEN_OFF + (size_t)bi * 128 + h] = 1e-20f + sd;
    } else {
        int h = t - 128;
        float s1 = 0.f, s2 = 0.f;
        #pragma unroll
        for (int r = 0; r < 8; ++r) {
            s1 += part[2 * 1024 + r * 128 + h];
            s2 += part[3 * 1024 + r * 128 + h];
        }
        ws[PSUM_OFF + (size_t)bi * 128 + h] = s1;
        ws[PSQ_OFF  + (size_t)bi * 128 + h] = s2;
    }
}

// ---------------------------------------------------------------------------
// Kernel C: per channel h: finalize BN-e scale/shift; x_feat = Ux + num/den,
// BN-x stats over 1024 rows, write x_new = x + relu(bn(x_feat)).
// ---------------------------------------------------------------------------
__global__ __launch_bounds__(256) void k_node(
    const float* __restrict__ x,
    const float* __restrict__ bn_x_g, const float* __restrict__ bn_x_b,
    const float* __restrict__ bn_e_g, const float* __restrict__ bn_e_b,
    float* ws, float* out_x)
{
    __shared__ float red[4 * 256];
    __shared__ float bc[3];
    int t = threadIdx.x, h = blockIdx.x;

    float s1 = 0.f, s2 = 0.f, sx = 0.f, sxx = 0.f, xf[4];
    #pragma unroll
    for (int q = 0; q < 4; ++q) {
        int r = t + 256 * q;
        size_t idx = (size_t)r * 128 + h;
        s1 += ws[PSUM_OFF + idx];
        s2 += ws[PSQ_OFF + idx];
        float v = ws[UX_OFF + idx] + ws[NUM_OFF + idx] / ws[DEN_OFF + idx];
        xf[q] = v; sx += v; sxx += v * v;
    }
    red[0*256+t] = s1; red[1*256+t] = s2; red[2*256+t] = sx; red[3*256+t] = sxx;
    __syncthreads();
    for (int off = 128; off >= 1; off >>= 1) {
        if (t < off) {
            #pragma unroll
            for (int a2 = 0; a2 < 4; ++a2) red[a2*256+t] += red[a2*256+t+off];
        }
        __syncthreads();
    }
    if (t == 0) {
        float me  = red[0*256] / (float)ME_;
        float ve  = red[1*256] / (float)ME_ - me * me;
        float sce = bn_e_g[h] * rsqrtf(ve + 1e-5f);
        ws[SCE_OFF + h] = sce;
        ws[SHE_OFF + h] = bn_e_b[h] - me * sce;
        float mx  = red[2*256] / 1024.0f;
        float vx  = red[3*256] / 1024.0f - mx * mx;
        bc[0] = mx;
        bc[1] = bn_x_g[h] * rsqrtf(vx + 1e-5f);
        bc[2] = bn_x_b[h];
    }
    __syncthreads();
    float mx = bc[0], scx = bc[1], bx = bc[2];
    #pragma unroll
    for (int q = 0; q < 4; ++q) {
        int r = t + 256 * q;
        size_t idx = (size_t)r * 128 + h;
        float bn = (xf[q] - mx) * scx + bx;
        out_x[idx] = x[idx] + fmaxf(bn, 0.0f);
    }
}

// ---------------------------------------------------------------------------
// Kernel D: e_new = e + relu(e_feat * scale_e[h] + shift_e[h])  (in place over
// the e_feat staged in out_e)
// ---------------------------------------------------------------------------
__global__ __launch_bounds__(256) void k_final_e(
    const float* __restrict__ e, const float* __restrict__ ws, float* out_e)
{
    __shared__ float sc[128], sh[128];
    int t = threadIdx.x;
    if (t < 128) sc[t] = ws[SCE_OFF + t];
    else         sh[t - 128] = ws[SHE_OFF + t - 128];
    __syncthreads();

    const float4* eg = (const float4*)e;
    float4*       og = (float4*)out_e;
    size_t n4 = (size_t)ME_ * 32;                 // 8388608 float4
    size_t stride = (size_t)gridDim.x * 256;
    for (size_t i4 = (size_t)blockIdx.x * 256 + t; i4 < n4; i4 += stride) {
        int hb = (int)(i4 & 31) * 4;
        float4 scv = *(const float4*)&sc[hb];
        float4 shv = *(const float4*)&sh[hb];
        float4 ef = og[i4];
        float4 ein = eg[i4];
        float4 r;
        r.x = ein.x + fmaxf(ef.x * scv.x + shv.x, 0.0f);
        r.y = ein.y + fmaxf(ef.y * scv.y + shv.y, 0.0f);
        r.z = ein.z + fmaxf(ef.z * scv.z + shv.z, 0.0f);
        r.w = ein.w + fmaxf(ef.w * scv.w + shv.w, 0.0f);
        og[i4] = r;
    }
}

extern "C" void kernel_launch(void* const* d_in, const int* in_sizes, int n_in,
                              void* d_out, int out_size, void* d_ws, size_t ws_size,
                              hipStream_t stream)
{
    const float* x      = (const float*)d_in[0];
    const float* e      = (const float*)d_in[1];
    const float* Ue_w   = (const float*)d_in[2];
    const float* Ue_b   = (const float*)d_in[3];
    const float* Ve_w   = (const float*)d_in[4];
    const float* Ve_b   = (const float*)d_in[5];
    const float* Un_w   = (const float*)d_in[6];
    const float* Un_b   = (const float*)d_in[7];
    const float* Vn_w   = (const float*)d_in[8];
    const float* Vn_b   = (const float*)d_in[9];
    const float* bn_x_g = (const float*)d_in[10];
    const float* bn_x_b = (const float*)d_in[11];
    const float* bn_e_g = (const float*)d_in[12];
    const float* bn_e_b = (const float*)d_in[13];

    float* out   = (float*)d_out;
    float* out_x = out;                 // 131072 floats
    float* out_e = out + 131072;        // 33554432 floats (also e_feat scratch)
    float* ws    = (float*)d_ws;

    k_linx   <<<128, 256, 0, stream>>>(x, Ve_w, Ve_b, Vn_w, Vn_b, Un_w, Un_b, ws);
    k_edge   <<<1024, 256, 0, stream>>>(e, Ue_w, Ue_b, out_e, ws);
    k_node   <<<128, 256, 0, stream>>>(x, bn_x_g, bn_x_b, bn_e_g, bn_e_b, ws, out_x);
    k_final_e<<<4096, 256, 0, stream>>>(e, ws, out_e);
}

// Round 2
// 215.215 us; speedup vs baseline: 1.4774x; 1.4774x over previous
//
#include <hip/hip_runtime.h>
#include <math.h>

typedef short bf16x8 __attribute__((ext_vector_type(8)));
typedef float f32x4 __attribute__((ext_vector_type(4)));

#define BB 4
#define NN 256
#define HH 128
#define ME_ (BB*NN*NN)        // 262144 edge rows

// workspace float offsets
#define VX_OFF   0            // 1024*128
#define VNX_OFF  131072
#define UX_OFF   262144
#define NUM_OFF  393216
#define DEN_OFF  524288
#define PSUM_OFF 655360       // per-(b,i) BN-e partial sums [1024][128]
#define PSQ_OFF  786432
#define SCE_OFF  917504       // [128]
#define SHE_OFF  917632       // [128]
#define W16_OFF  917760       // 16384 ushort (32 KB) bf16 Ue_w

__device__ inline short f2bf(float f) {
    unsigned u = __builtin_bit_cast(unsigned, f);
    u += 0x7FFFu + ((u >> 16) & 1u);      // round-to-nearest-even
    return (short)(u >> 16);
}

// ---------------------------------------------------------------------------
// Kernel P: Ue_w fp32 -> bf16 (once)
// ---------------------------------------------------------------------------
__global__ __launch_bounds__(256) void k_prep(const float* __restrict__ W,
                                              unsigned short* __restrict__ W16)
{
    int i = blockIdx.x * 256 + threadIdx.x;      // grid 64 -> 16384
    W16[i] = (unsigned short)f2bf(W[i]);
}

// ---------------------------------------------------------------------------
// Kernel A: Vx = x@Ve^T+b, Vnx = x@Vn^T+b, Ux = x@Un^T+b   (1024 rows, H=128)
// ---------------------------------------------------------------------------
__global__ __launch_bounds__(256) void k_linx(
    const float* __restrict__ x,
    const float* __restrict__ Ve_w, const float* __restrict__ Ve_b,
    const float* __restrict__ Vn_w, const float* __restrict__ Vn_b,
    const float* __restrict__ Un_w, const float* __restrict__ Un_b,
    float* ws)
{
    __shared__ float xs[8 * 128];
    int t = threadIdx.x;
    int rowbase = blockIdx.x * 8;

    const float4* xg = (const float4*)(x + (size_t)rowbase * 128);
    ((float4*)xs)[t] = xg[t];
    __syncthreads();

    int h = t & 127, rh = t >> 7;
    float accV[4], accN[4], accU[4];
    float bV = Ve_b[h], bN = Vn_b[h], bU = Un_b[h];
    #pragma unroll
    for (int q = 0; q < 4; ++q) { accV[q] = bV; accN[q] = bN; accU[q] = bU; }

    const float4* wV = (const float4*)(Ve_w + (size_t)h * 128);
    const float4* wN = (const float4*)(Vn_w + (size_t)h * 128);
    const float4* wU = (const float4*)(Un_w + (size_t)h * 128);

    #pragma unroll 4
    for (int k4 = 0; k4 < 32; ++k4) {
        float4 wv = wV[k4], wn = wN[k4], wu = wU[k4];
        #pragma unroll
        for (int q = 0; q < 4; ++q) {
            float4 xv = *(const float4*)&xs[(rh + 2 * q) * 128 + k4 * 4];
            accV[q] += xv.x*wv.x + xv.y*wv.y + xv.z*wv.z + xv.w*wv.w;
            accN[q] += xv.x*wn.x + xv.y*wn.y + xv.z*wn.z + xv.w*wn.w;
            accU[q] += xv.x*wu.x + xv.y*wu.y + xv.z*wu.z + xv.w*wu.w;
        }
    }
    #pragma unroll
    for (int q = 0; q < 4; ++q) {
        size_t idx = (size_t)(rowbase + rh + 2 * q) * 128 + h;
        ws[VX_OFF  + idx] = accV[q];
        ws[VNX_OFF + idx] = accN[q];
        ws[UX_OFF  + idx] = accU[q];
    }
}

// ---------------------------------------------------------------------------
// Kernel B (MFMA): per (b,i): e_feat = bf16(e)@bf16(Ue)^T + Ue_b + Vx_i + Vx_j
// store e_feat fp32 to out_e; gates=sigmoid; num/den row sums; BN-e partials.
// 4 waves; wave w owns j-rows [64w, 64w+64); 16x16x32 MFMA tiles.
// ---------------------------------------------------------------------------
__global__ __launch_bounds__(256) void k_edge(
    const float* __restrict__ e,
    const unsigned short* __restrict__ W16,
    const float* __restrict__ Ue_b,
    float* __restrict__ out_e, float* __restrict__ ws)
{
    __shared__ short Wl[16384];     // 32 KB bf16 W, XOR-swizzled (byte ^= (row&7)<<4)
    __shared__ float red[2048];     // [4 stats][4 waves][128]
    int t   = threadIdx.x;
    int bi  = blockIdx.x;           // (b,i), 0..1023
    int b   = bi >> 8;
    int wid = t >> 6;
    int l   = t & 63;
    int hsub = l & 15, g = l >> 4;

    // stage W16 -> LDS, swizzled by 16B unit within each 256B row
    const int4* Wg = (const int4*)W16;
    #pragma unroll
    for (int p = 0; p < 8; ++p) {
        int s = t + 256 * p;                 // 2048 chunks of 16B
        int r = s >> 4, c = s & 15;
        int addr = r * 256 + ((c * 16) ^ ((r & 7) << 4));
        *(int4*)((char*)Wl + addr) = Wg[s];
    }
    __syncthreads();

    const float* Vx  = ws + VX_OFF;
    const float* Vnx = ws + VNX_OFF;

    float biasv[8];
    #pragma unroll
    for (int ct = 0; ct < 8; ++ct) {
        int h = ct * 16 + hsub;
        biasv[ct] = Ue_b[h] + Vx[(size_t)bi * 128 + h];
    }

    float num[8] = {0,0,0,0,0,0,0,0}, den[8] = {0,0,0,0,0,0,0,0};
    float se[8]  = {0,0,0,0,0,0,0,0}, sq[8]  = {0,0,0,0,0,0,0,0};

    const float* eb = e + (size_t)bi * 32768;
    float* oute = out_e + (size_t)bi * 32768;
    int swz = (hsub & 7) << 4;               // (row&7)<<4 with row=ct*16+hsub

    for (int rt = 0; rt < 4; ++rt) {
        int jb = (wid * 4 + rt) * 16;        // j-tile base

        // A fragments: lane -> row jb+hsub, k = kc*32 + g*8 .. +8 (fp32->bf16)
        bf16x8 afr[4];
        #pragma unroll
        for (int kc = 0; kc < 4; ++kc) {
            const float4* p = (const float4*)(eb + (size_t)(jb + hsub) * 128 + kc * 32 + g * 8);
            float4 f0 = p[0], f1 = p[1];
            bf16x8 a;
            a[0] = f2bf(f0.x); a[1] = f2bf(f0.y); a[2] = f2bf(f0.z); a[3] = f2bf(f0.w);
            a[4] = f2bf(f1.x); a[5] = f2bf(f1.y); a[6] = f2bf(f1.z); a[7] = f2bf(f1.w);
            afr[kc] = a;
        }

        #pragma unroll
        for (int ct = 0; ct < 8; ++ct) {
            int h = ct * 16 + hsub;          // B row = C col = channel
            f32x4 acc = {0.f, 0.f, 0.f, 0.f};
            #pragma unroll
            for (int kc = 0; kc < 4; ++kc) {
                bf16x8 bfr = *(const bf16x8*)((const char*)Wl +
                                h * 256 + ((kc * 64 + g * 16) ^ swz));
                acc = __builtin_amdgcn_mfma_f32_16x16x32_bf16(afr[kc], bfr, acc, 0, 0, 0);
            }
            float bih = biasv[ct];
            #pragma unroll
            for (int r = 0; r < 4; ++r) {
                int j = jb + g * 4 + r;      // C row = j
                float v = acc[r] + bih + Vx[(size_t)(b * 256 + j) * 128 + h];
                oute[(size_t)j * 128 + h] = v;
                float gv = 1.0f / (1.0f + __expf(-v));
                num[ct] += gv * Vnx[(size_t)(b * 256 + j) * 128 + h];
                den[ct] += gv;
                se[ct]  += v;
                sq[ct]  += v * v;
            }
        }
    }

    // reduce lanes sharing h (l, l+16, l+32, l+48), then per-wave partials
    #pragma unroll
    for (int ct = 0; ct < 8; ++ct) {
        float n = num[ct], d = den[ct], s1 = se[ct], s2 = sq[ct];
        n  += __shfl_xor(n, 32);  n  += __shfl_xor(n, 16);
        d  += __shfl_xor(d, 32);  d  += __shfl_xor(d, 16);
        s1 += __shfl_xor(s1, 32); s1 += __shfl_xor(s1, 16);
        s2 += __shfl_xor(s2, 32); s2 += __shfl_xor(s2, 16);
        if (l < 16) {
            int h = ct * 16 + l;
            red[0 * 512 + wid * 128 + h] = n;
            red[1 * 512 + wid * 128 + h] = d;
            red[2 * 512 + wid * 128 + h] = s1;
            red[3 * 512 + wid * 128 + h] = s2;
        }
    }
    __syncthreads();
    if (t < 128) {
        int h = t;
        float sn = 0.f, sd = 0.f;
        #pragma unroll
        for (int w = 0; w < 4; ++w) {
            sn += red[0 * 512 + w * 128 + h];
            sd += red[1 * 512 + w * 128 + h];
        }
        ws[NUM_OFF + (size_t)bi * 128 + h] = sn;
        ws[DEN_OFF + (size_t)bi * 128 + h] = 1e-20f + sd;
    } else {
        int h = t - 128;
        float s1 = 0.f, s2 = 0.f;
        #pragma unroll
        for (int w = 0; w < 4; ++w) {
            s1 += red[2 * 512 + w * 128 + h];
            s2 += red[3 * 512 + w * 128 + h];
        }
        ws[PSUM_OFF + (size_t)bi * 128 + h] = s1;
        ws[PSQ_OFF  + (size_t)bi * 128 + h] = s2;
    }
}

// ---------------------------------------------------------------------------
// Kernel C: per channel h: finalize BN-e scale/shift; x_feat = Ux + num/den,
// BN-x stats over 1024 rows, write x_new = x + relu(bn(x_feat)).
// ---------------------------------------------------------------------------
__global__ __launch_bounds__(256) void k_node(
    const float* __restrict__ x,
    const float* __restrict__ bn_x_g, const float* __restrict__ bn_x_b,
    const float* __restrict__ bn_e_g, const float* __restrict__ bn_e_b,
    float* ws, float* out_x)
{
    __shared__ float red[4 * 256];
    __shared__ float bc[3];
    int t = threadIdx.x, h = blockIdx.x;

    float s1 = 0.f, s2 = 0.f, sx = 0.f, sxx = 0.f, xf[4];
    #pragma unroll
    for (int q = 0; q < 4; ++q) {
        int r = t + 256 * q;
        size_t idx = (size_t)r * 128 + h;
        s1 += ws[PSUM_OFF + idx];
        s2 += ws[PSQ_OFF + idx];
        float v = ws[UX_OFF + idx] + ws[NUM_OFF + idx] / ws[DEN_OFF + idx];
        xf[q] = v; sx += v; sxx += v * v;
    }
    red[0*256+t] = s1; red[1*256+t] = s2; red[2*256+t] = sx; red[3*256+t] = sxx;
    __syncthreads();
    for (int off = 128; off >= 1; off >>= 1) {
        if (t < off) {
            #pragma unroll
            for (int a2 = 0; a2 < 4; ++a2) red[a2*256+t] += red[a2*256+t+off];
        }
        __syncthreads();
    }
    if (t == 0) {
        float me  = red[0*256] / (float)ME_;
        float ve  = red[1*256] / (float)ME_ - me * me;
        float sce = bn_e_g[h] * rsqrtf(ve + 1e-5f);
        ws[SCE_OFF + h] = sce;
        ws[SHE_OFF + h] = bn_e_b[h] - me * sce;
        float mx  = red[2*256] / 1024.0f;
        float vx  = red[3*256] / 1024.0f - mx * mx;
        bc[0] = mx;
        bc[1] = bn_x_g[h] * rsqrtf(vx + 1e-5f);
        bc[2] = bn_x_b[h];
    }
    __syncthreads();
    float mx = bc[0], scx = bc[1], bx = bc[2];
    #pragma unroll
    for (int q = 0; q < 4; ++q) {
        int r = t + 256 * q;
        size_t idx = (size_t)r * 128 + h;
        float bn = (xf[q] - mx) * scx + bx;
        out_x[idx] = x[idx] + fmaxf(bn, 0.0f);
    }
}

// ---------------------------------------------------------------------------
// Kernel D: e_new = e + relu(e_feat * scale_e[h] + shift_e[h])  (in place over
// the fp32 e_feat staged in out_e)
// ---------------------------------------------------------------------------
__global__ __launch_bounds__(256) void k_final_e(
    const float* __restrict__ e, const float* __restrict__ ws, float* out_e)
{
    __shared__ float sc[128], sh[128];
    int t = threadIdx.x;
    if (t < 128) sc[t] = ws[SCE_OFF + t];
    else         sh[t - 128] = ws[SHE_OFF + t - 128];
    __syncthreads();

    const float4* eg = (const float4*)e;
    float4*       og = (float4*)out_e;
    size_t n4 = (size_t)ME_ * 32;
    size_t stride = (size_t)gridDim.x * 256;
    for (size_t i4 = (size_t)blockIdx.x * 256 + t; i4 < n4; i4 += stride) {
        int hb = (int)(i4 & 31) * 4;
        float4 scv = *(const float4*)&sc[hb];
        float4 shv = *(const float4*)&sh[hb];
        float4 ef = og[i4];
        float4 ein = eg[i4];
        float4 r;
        r.x = ein.x + fmaxf(ef.x * scv.x + shv.x, 0.0f);
        r.y = ein.y + fmaxf(ef.y * scv.y + shv.y, 0.0f);
        r.z = ein.z + fmaxf(ef.z * scv.z + shv.z, 0.0f);
        r.w = ein.w + fmaxf(ef.w * scv.w + shv.w, 0.0f);
        og[i4] = r;
    }
}

extern "C" void kernel_launch(void* const* d_in, const int* in_sizes, int n_in,
                              void* d_out, int out_size, void* d_ws, size_t ws_size,
                              hipStream_t stream)
{
    const float* x      = (const float*)d_in[0];
    const float* e      = (const float*)d_in[1];
    const float* Ue_w   = (const float*)d_in[2];
    const float* Ue_b   = (const float*)d_in[3];
    const float* Ve_w   = (const float*)d_in[4];
    const float* Ve_b   = (const float*)d_in[5];
    const float* Un_w   = (const float*)d_in[6];
    const float* Un_b   = (const float*)d_in[7];
    const float* Vn_w   = (const float*)d_in[8];
    const float* Vn_b   = (const float*)d_in[9];
    const float* bn_x_g = (const float*)d_in[10];
    const float* bn_x_b = (const float*)d_in[11];
    const float* bn_e_g = (const float*)d_in[12];
    const float* bn_e_b = (const float*)d_in[13];

    float* out   = (float*)d_out;
    float* out_x = out;                 // 131072 floats
    float* out_e = out + 131072;        // 33554432 floats (also e_feat scratch)
    float* ws    = (float*)d_ws;
    unsigned short* W16 = (unsigned short*)(ws + W16_OFF);

    k_prep   <<<64, 256, 0, stream>>>(Ue_w, W16);
    k_linx   <<<128, 256, 0, stream>>>(x, Ve_w, Ve_b, Vn_w, Vn_b, Un_w, Un_b, ws);
    k_edge   <<<1024, 256, 0, stream>>>(e, W16, Ue_b, out_e, ws);
    k_node   <<<128, 256, 0, stream>>>(x, bn_x_g, bn_x_b, bn_e_g, bn_e_b, ws, out_x);
    k_final_e<<<4096, 256, 0, stream>>>(e, ws, out_e);
}